// Round 1
// baseline (4979.568 us; speedup 1.0000x reference)
//
#include <hip/hip_runtime.h>
#include <cstddef>

#define D 128
#define D4 32
#define ROWS 32

__global__ __launch_bounds__(256) void edge_agg_kernel(
    const float* __restrict__ x, const int* __restrict__ ei,
    const float* __restrict__ ea, float* __restrict__ agg, int E) {
  int tid = blockIdx.x * 256 + threadIdx.x;
  int lane = tid & 31;            // which float4 of the 128-float row
  int eg = tid >> 5;              // edge group
  int negs = (gridDim.x * 256) >> 5;
  for (int e = eg; e < E; e += negs) {
    int src = ei[e];
    int dst = ei[E + e];
    float4 xv = *reinterpret_cast<const float4*>(x + (size_t)src * D + lane * 4);
    float4 ev = *reinterpret_cast<const float4*>(ea + (size_t)e * D + lane * 4);
    float4 m;
    m.x = fmaxf(xv.x + ev.x, 0.0f);
    m.y = fmaxf(xv.y + ev.y, 0.0f);
    m.z = fmaxf(xv.z + ev.z, 0.0f);
    m.w = fmaxf(xv.w + ev.w, 0.0f);
    float* ap = agg + (size_t)dst * D + lane * 4;
    atomicAdd(ap + 0, m.x);
    atomicAdd(ap + 1, m.y);
    atomicAdd(ap + 2, m.z);
    atomicAdd(ap + 3, m.w);
  }
}

// C[4 rows][4 cols] register tile per thread. 256 threads = 8 row-threads x 32 col-threads.
__device__ __forceinline__ void gemm_tile(const float* hs, const float* Ws,
                                          int rtid, int ctid, float4 acc[4]) {
  const float4* hs4 = reinterpret_cast<const float4*>(hs);
  const float4* Ws4 = reinterpret_cast<const float4*>(Ws);
#pragma unroll
  for (int i = 0; i < 4; ++i) acc[i] = make_float4(0.f, 0.f, 0.f, 0.f);
#pragma unroll 4
  for (int k4 = 0; k4 < D4; ++k4) {
    float ax[4][4];
#pragma unroll
    for (int i = 0; i < 4; ++i) {
      float4 t = hs4[(rtid * 4 + i) * D4 + k4];
      ax[i][0] = t.x; ax[i][1] = t.y; ax[i][2] = t.z; ax[i][3] = t.w;
    }
#pragma unroll
    for (int kk = 0; kk < 4; ++kk) {
      float4 b = Ws4[(k4 * 4 + kk) * D4 + ctid];
#pragma unroll
      for (int i = 0; i < 4; ++i) {
        acc[i].x = fmaf(ax[i][kk], b.x, acc[i].x);
        acc[i].y = fmaf(ax[i][kk], b.y, acc[i].y);
        acc[i].z = fmaf(ax[i][kk], b.z, acc[i].z);
        acc[i].w = fmaf(ax[i][kk], b.w, acc[i].w);
      }
    }
  }
}

__global__ __launch_bounds__(256) void mlp_bn_kernel(
    const float* __restrict__ x, const float* __restrict__ agg,
    const float* __restrict__ W1, const float* __restrict__ b1,
    const float* __restrict__ W2, const float* __restrict__ b2,
    const float* __restrict__ epsp, const float* __restrict__ mask,
    const float* __restrict__ gamma, const float* __restrict__ beta,
    const float* __restrict__ rmean, const float* __restrict__ rvar,
    const float* __restrict__ x_in, float* __restrict__ out,
    int N, int is_last) {
  __shared__ float Ws[D * D];     // 64 KB
  __shared__ float hs[ROWS * D];  // 16 KB
  const int tid = threadIdx.x;
  const int ctid = tid & 31;
  const int rtid = tid >> 5;
  const int r0 = blockIdx.x * ROWS;
  const float one_eps = 1.0f + epsp[0];

  float4* hs4 = reinterpret_cast<float4*>(hs);
  // stage h = (1+eps)*x + agg  for our 32 rows
  for (int j = tid; j < ROWS * D4; j += 256) {
    int row = j >> 5;
    int c4 = j & 31;
    int gr = r0 + row;
    float4 v = make_float4(0.f, 0.f, 0.f, 0.f);
    if (gr < N) {
      float4 xv = *reinterpret_cast<const float4*>(x + (size_t)gr * D + c4 * 4);
      float4 av = *reinterpret_cast<const float4*>(agg + (size_t)gr * D + c4 * 4);
      v.x = fmaf(one_eps, xv.x, av.x);
      v.y = fmaf(one_eps, xv.y, av.y);
      v.z = fmaf(one_eps, xv.z, av.z);
      v.w = fmaf(one_eps, xv.w, av.w);
    }
    hs4[j] = v;
  }
  // stage W1
  {
    float4* Ws4 = reinterpret_cast<float4*>(Ws);
    const float4* W14 = reinterpret_cast<const float4*>(W1);
    for (int j = tid; j < D * D4; j += 256) Ws4[j] = W14[j];
  }
  __syncthreads();

  float4 acc1[4];
  gemm_tile(hs, Ws, rtid, ctid, acc1);
  __syncthreads();  // everyone done reading hs/Ws

  // t = relu(h@W1 + b1) -> hs ; stage W2 -> Ws
  {
    float4 b1v = reinterpret_cast<const float4*>(b1)[ctid];
#pragma unroll
    for (int i = 0; i < 4; ++i) {
      float4 t;
      t.x = fmaxf(acc1[i].x + b1v.x, 0.f);
      t.y = fmaxf(acc1[i].y + b1v.y, 0.f);
      t.z = fmaxf(acc1[i].z + b1v.z, 0.f);
      t.w = fmaxf(acc1[i].w + b1v.w, 0.f);
      hs4[(rtid * 4 + i) * D4 + ctid] = t;
    }
    float4* Ws4 = reinterpret_cast<float4*>(Ws);
    const float4* W24 = reinterpret_cast<const float4*>(W2);
    for (int j = tid; j < D * D4; j += 256) Ws4[j] = W24[j];
  }
  __syncthreads();

  float4 acc2[4];
  gemm_tile(hs, Ws, rtid, ctid, acc2);

  // epilogue: v = mask*h2 + x ; BN(eval) ; maybe final relu + outer residual
  float4 b2v = reinterpret_cast<const float4*>(b2)[ctid];
  float4 gv = reinterpret_cast<const float4*>(gamma)[ctid];
  float4 bv = reinterpret_cast<const float4*>(beta)[ctid];
  float4 rmv = reinterpret_cast<const float4*>(rmean)[ctid];
  float4 rvv = reinterpret_cast<const float4*>(rvar)[ctid];
  float4 sc;
  sc.x = gv.x * rsqrtf(rvv.x + 1e-5f);
  sc.y = gv.y * rsqrtf(rvv.y + 1e-5f);
  sc.z = gv.z * rsqrtf(rvv.z + 1e-5f);
  sc.w = gv.w * rsqrtf(rvv.w + 1e-5f);
#pragma unroll
  for (int i = 0; i < 4; ++i) {
    int gr = r0 + rtid * 4 + i;
    if (gr >= N) continue;
    float mk = mask[gr];
    float4 xv = *reinterpret_cast<const float4*>(x + (size_t)gr * D + ctid * 4);
    float4 v;
    v.x = fmaf(mk, acc2[i].x + b2v.x, xv.x);
    v.y = fmaf(mk, acc2[i].y + b2v.y, xv.y);
    v.z = fmaf(mk, acc2[i].z + b2v.z, xv.z);
    v.w = fmaf(mk, acc2[i].w + b2v.w, xv.w);
    v.x = fmaf(v.x - rmv.x, sc.x, bv.x);
    v.y = fmaf(v.y - rmv.y, sc.y, bv.y);
    v.z = fmaf(v.z - rmv.z, sc.z, bv.z);
    v.w = fmaf(v.w - rmv.w, sc.w, bv.w);
    if (is_last) {
      float4 xi = *reinterpret_cast<const float4*>(x_in + (size_t)gr * D + ctid * 4);
      v.x = xi.x + fmaxf(v.x, 0.f);
      v.y = xi.y + fmaxf(v.y, 0.f);
      v.z = xi.z + fmaxf(v.z, 0.f);
      v.w = xi.w + fmaxf(v.w, 0.f);
    }
    *reinterpret_cast<float4*>(out + (size_t)gr * D + ctid * 4) = v;
  }
}

extern "C" void kernel_launch(void* const* d_in, const int* in_sizes, int n_in,
                              void* d_out, int out_size, void* d_ws, size_t ws_size,
                              hipStream_t stream) {
  const float* x_in  = (const float*)d_in[0];
  const int*   ei    = (const int*)d_in[1];
  const float* ea    = (const float*)d_in[2];
  const float* masks = (const float*)d_in[3];
  const float* W1    = (const float*)d_in[4];
  const float* b1    = (const float*)d_in[5];
  const float* W2    = (const float*)d_in[6];
  const float* b2    = (const float*)d_in[7];
  const float* eps   = (const float*)d_in[8];
  const float* gamma = (const float*)d_in[9];
  const float* beta  = (const float*)d_in[10];
  const float* rmean = (const float*)d_in[11];
  const float* rvar  = (const float*)d_in[12];
  const int N = in_sizes[0] / D;
  const int E = in_sizes[1] / 2;
  const int C = in_sizes[8];

  float* agg  = (float*)d_ws;       // N*D floats
  float* xbuf = (float*)d_out;      // ping buffer doubles as output
  const float* xc = x_in;
  const int mlp_blocks = (N + ROWS - 1) / ROWS;

  for (int c = 0; c < C; ++c) {
    hipMemsetAsync(agg, 0, (size_t)N * D * sizeof(float), stream);
    edge_agg_kernel<<<8192, 256, 0, stream>>>(xc, ei, ea, agg, E);
    mlp_bn_kernel<<<mlp_blocks, 256, 0, stream>>>(
        xc, agg,
        W1 + (size_t)c * D * D, b1 + (size_t)c * D,
        W2 + (size_t)c * D * D, b2 + (size_t)c * D,
        eps + c, masks + (size_t)c * N,
        gamma + (size_t)c * D, beta + (size_t)c * D,
        rmean + (size_t)c * D, rvar + (size_t)c * D,
        x_in, xbuf, N, (c == C - 1) ? 1 : 0);
    xc = xbuf;
  }
}

// Round 2
// 1141.933 us; speedup vs baseline: 4.3606x; 4.3606x over previous
//
#include <hip/hip_runtime.h>
#include <cstddef>

#define D 128
#define D4 32
#define ROWS 32
#define CHUNK 1024

// ---------------- CSR build (once per call) ----------------
__global__ __launch_bounds__(256) void hist_kernel(const int* __restrict__ ei,
                                                   int* __restrict__ deg, int E) {
  int e = blockIdx.x * 256 + threadIdx.x;
  if (e < E) atomicAdd(&deg[ei[E + e]], 1);
}

__global__ __launch_bounds__(256) void partial_kernel(const int* __restrict__ deg,
                                                      int* __restrict__ partial, int N) {
  __shared__ int s[256];
  int base = blockIdx.x * CHUNK;
  int sum = 0;
  for (int j = threadIdx.x; j < CHUNK; j += 256) {
    int idx = base + j;
    sum += (idx < N) ? deg[idx] : 0;
  }
  s[threadIdx.x] = sum;
  __syncthreads();
  for (int ofs = 128; ofs > 0; ofs >>= 1) {
    if (threadIdx.x < ofs) s[threadIdx.x] += s[threadIdx.x + ofs];
    __syncthreads();
  }
  if (threadIdx.x == 0) partial[blockIdx.x] = s[0];
}

__global__ void scanpart_kernel(int* partial, int nb) {
  if (threadIdx.x == 0) {
    int run = 0;
    for (int i = 0; i < nb; ++i) { int v = partial[i]; partial[i] = run; run += v; }
  }
}

__global__ void chunkscan_kernel(const int* __restrict__ deg, const int* __restrict__ partial,
                                 int* __restrict__ off, int N) {
  if (threadIdx.x == 0) {
    int base = blockIdx.x * CHUNK;
    int run = partial[blockIdx.x];
    int end = min(base + CHUNK, N);
    for (int i = base; i < end; ++i) { off[i] = run; run += deg[i]; }
    if (end == N) off[N] = run;
  }
}

__global__ __launch_bounds__(256) void scatter_kernel(const int* __restrict__ ei,
                                                      const int* __restrict__ off,
                                                      int* __restrict__ cursor,
                                                      int* __restrict__ eperm,
                                                      int* __restrict__ sperm, int E) {
  int e = blockIdx.x * 256 + threadIdx.x;
  if (e < E) {
    int s = ei[e];
    int d = ei[E + e];
    int p = off[d] + atomicAdd(&cursor[d], 1);
    eperm[p] = e;
    sperm[p] = s;
  }
}

// ---------------- per-layer: gather-aggregate, fused h = (1+eps)x + agg ----------------
__global__ __launch_bounds__(256) void agg_h_kernel(
    const float* __restrict__ x, const float* __restrict__ ea,
    const int* __restrict__ off, const int* __restrict__ eperm,
    const int* __restrict__ sperm, const float* __restrict__ epsp,
    float* __restrict__ h, int N) {
  int row = blockIdx.x * 8 + (threadIdx.x >> 5);
  int lane = threadIdx.x & 31;
  if (row >= N) return;
  int beg = off[row], end = off[row + 1];
  float4 acc = make_float4(0.f, 0.f, 0.f, 0.f);
  for (int i = beg; i < end; ++i) {
    int e = eperm[i];
    int s = sperm[i];
    float4 xv = *reinterpret_cast<const float4*>(x + (size_t)s * D + lane * 4);
    float4 ev = *reinterpret_cast<const float4*>(ea + (size_t)e * D + lane * 4);
    acc.x += fmaxf(xv.x + ev.x, 0.f);
    acc.y += fmaxf(xv.y + ev.y, 0.f);
    acc.z += fmaxf(xv.z + ev.z, 0.f);
    acc.w += fmaxf(xv.w + ev.w, 0.f);
  }
  float one_eps = 1.0f + epsp[0];
  float4 xd = *reinterpret_cast<const float4*>(x + (size_t)row * D + lane * 4);
  float4 hv;
  hv.x = fmaf(one_eps, xd.x, acc.x);
  hv.y = fmaf(one_eps, xd.y, acc.y);
  hv.z = fmaf(one_eps, xd.z, acc.z);
  hv.w = fmaf(one_eps, xd.w, acc.w);
  *reinterpret_cast<float4*>(h + (size_t)row * D + lane * 4) = hv;
}

// ---------------- MLP + mask residual + BN (+ final relu/residual) ----------------
__device__ __forceinline__ void gemm_tile(const float* hs, const float* Ws,
                                          int rtid, int ctid, float4 acc[4]) {
  const float4* hs4 = reinterpret_cast<const float4*>(hs);
  const float4* Ws4 = reinterpret_cast<const float4*>(Ws);
#pragma unroll
  for (int i = 0; i < 4; ++i) acc[i] = make_float4(0.f, 0.f, 0.f, 0.f);
#pragma unroll 4
  for (int k4 = 0; k4 < D4; ++k4) {
    float ax[4][4];
#pragma unroll
    for (int i = 0; i < 4; ++i) {
      float4 t = hs4[(rtid * 4 + i) * D4 + k4];
      ax[i][0] = t.x; ax[i][1] = t.y; ax[i][2] = t.z; ax[i][3] = t.w;
    }
#pragma unroll
    for (int kk = 0; kk < 4; ++kk) {
      float4 b = Ws4[(k4 * 4 + kk) * D4 + ctid];
#pragma unroll
      for (int i = 0; i < 4; ++i) {
        acc[i].x = fmaf(ax[i][kk], b.x, acc[i].x);
        acc[i].y = fmaf(ax[i][kk], b.y, acc[i].y);
        acc[i].z = fmaf(ax[i][kk], b.z, acc[i].z);
        acc[i].w = fmaf(ax[i][kk], b.w, acc[i].w);
      }
    }
  }
}

__global__ __launch_bounds__(256) void mlp_bn_kernel(
    const float* __restrict__ x, const float* __restrict__ h,
    const float* __restrict__ W1, const float* __restrict__ b1,
    const float* __restrict__ W2, const float* __restrict__ b2,
    const float* __restrict__ mask,
    const float* __restrict__ gamma, const float* __restrict__ beta,
    const float* __restrict__ rmean, const float* __restrict__ rvar,
    const float* __restrict__ x_in, float* __restrict__ out,
    int N, int is_last) {
  __shared__ float Ws[D * D];     // 64 KB
  __shared__ float hs[ROWS * D];  // 16 KB
  const int tid = threadIdx.x;
  const int ctid = tid & 31;
  const int rtid = tid >> 5;
  const int r0 = blockIdx.x * ROWS;

  float4* hs4 = reinterpret_cast<float4*>(hs);
  // stage h (already = (1+eps)x + agg) for our 32 rows
  for (int j = tid; j < ROWS * D4; j += 256) {
    int row = j >> 5;
    int c4 = j & 31;
    int gr = r0 + row;
    float4 v = make_float4(0.f, 0.f, 0.f, 0.f);
    if (gr < N) v = *reinterpret_cast<const float4*>(h + (size_t)gr * D + c4 * 4);
    hs4[j] = v;
  }
  // stage W1
  {
    float4* Ws4 = reinterpret_cast<float4*>(Ws);
    const float4* W14 = reinterpret_cast<const float4*>(W1);
    for (int j = tid; j < D * D4; j += 256) Ws4[j] = W14[j];
  }
  __syncthreads();

  float4 acc1[4];
  gemm_tile(hs, Ws, rtid, ctid, acc1);
  __syncthreads();

  // t = relu(h@W1 + b1) -> hs ; stage W2 -> Ws
  {
    float4 b1v = reinterpret_cast<const float4*>(b1)[ctid];
#pragma unroll
    for (int i = 0; i < 4; ++i) {
      float4 t;
      t.x = fmaxf(acc1[i].x + b1v.x, 0.f);
      t.y = fmaxf(acc1[i].y + b1v.y, 0.f);
      t.z = fmaxf(acc1[i].z + b1v.z, 0.f);
      t.w = fmaxf(acc1[i].w + b1v.w, 0.f);
      hs4[(rtid * 4 + i) * D4 + ctid] = t;
    }
    float4* Ws4 = reinterpret_cast<float4*>(Ws);
    const float4* W24 = reinterpret_cast<const float4*>(W2);
    for (int j = tid; j < D * D4; j += 256) Ws4[j] = W24[j];
  }
  __syncthreads();

  float4 acc2[4];
  gemm_tile(hs, Ws, rtid, ctid, acc2);

  float4 b2v = reinterpret_cast<const float4*>(b2)[ctid];
  float4 gv = reinterpret_cast<const float4*>(gamma)[ctid];
  float4 bv = reinterpret_cast<const float4*>(beta)[ctid];
  float4 rmv = reinterpret_cast<const float4*>(rmean)[ctid];
  float4 rvv = reinterpret_cast<const float4*>(rvar)[ctid];
  float4 sc;
  sc.x = gv.x * rsqrtf(rvv.x + 1e-5f);
  sc.y = gv.y * rsqrtf(rvv.y + 1e-5f);
  sc.z = gv.z * rsqrtf(rvv.z + 1e-5f);
  sc.w = gv.w * rsqrtf(rvv.w + 1e-5f);
#pragma unroll
  for (int i = 0; i < 4; ++i) {
    int gr = r0 + rtid * 4 + i;
    if (gr >= N) continue;
    float mk = mask[gr];
    float4 xv = *reinterpret_cast<const float4*>(x + (size_t)gr * D + ctid * 4);
    float4 v;
    v.x = fmaf(mk, acc2[i].x + b2v.x, xv.x);
    v.y = fmaf(mk, acc2[i].y + b2v.y, xv.y);
    v.z = fmaf(mk, acc2[i].z + b2v.z, xv.z);
    v.w = fmaf(mk, acc2[i].w + b2v.w, xv.w);
    v.x = fmaf(v.x - rmv.x, sc.x, bv.x);
    v.y = fmaf(v.y - rmv.y, sc.y, bv.y);
    v.z = fmaf(v.z - rmv.z, sc.z, bv.z);
    v.w = fmaf(v.w - rmv.w, sc.w, bv.w);
    if (is_last) {
      float4 xi = *reinterpret_cast<const float4*>(x_in + (size_t)gr * D + ctid * 4);
      v.x = xi.x + fmaxf(v.x, 0.f);
      v.y = xi.y + fmaxf(v.y, 0.f);
      v.z = xi.z + fmaxf(v.z, 0.f);
      v.w = xi.w + fmaxf(v.w, 0.f);
    }
    *reinterpret_cast<float4*>(out + (size_t)gr * D + ctid * 4) = v;
  }
}

extern "C" void kernel_launch(void* const* d_in, const int* in_sizes, int n_in,
                              void* d_out, int out_size, void* d_ws, size_t ws_size,
                              hipStream_t stream) {
  const float* x_in  = (const float*)d_in[0];
  const int*   ei    = (const int*)d_in[1];
  const float* ea    = (const float*)d_in[2];
  const float* masks = (const float*)d_in[3];
  const float* W1    = (const float*)d_in[4];
  const float* b1    = (const float*)d_in[5];
  const float* W2    = (const float*)d_in[6];
  const float* b2    = (const float*)d_in[7];
  const float* eps   = (const float*)d_in[8];
  const float* gamma = (const float*)d_in[9];
  const float* beta  = (const float*)d_in[10];
  const float* rmean = (const float*)d_in[11];
  const float* rvar  = (const float*)d_in[12];
  const int N = in_sizes[0] / D;
  const int E = in_sizes[1] / 2;
  const int C = in_sizes[8];
  const int nb = (N + CHUNK - 1) / CHUNK;

  // workspace layout
  char* w = (char*)d_ws;
  float* h     = (float*)w;  w += (size_t)N * D * sizeof(float);
  int* deg     = (int*)w;    w += (size_t)N * sizeof(int);
  int* off     = (int*)w;    w += (size_t)(N + 1) * sizeof(int);
  int* cursor  = (int*)w;    w += (size_t)N * sizeof(int);
  int* partial = (int*)w;    w += (size_t)(nb + 1) * sizeof(int);
  int* eperm   = (int*)w;    w += (size_t)E * sizeof(int);
  int* sperm   = (int*)w;

  // ---- build CSR (edge_index is layer-invariant) ----
  hipMemsetAsync(deg, 0, (size_t)N * sizeof(int), stream);
  hipMemsetAsync(cursor, 0, (size_t)N * sizeof(int), stream);
  hist_kernel<<<(E + 255) / 256, 256, 0, stream>>>(ei, deg, E);
  partial_kernel<<<nb, 256, 0, stream>>>(deg, partial, N);
  scanpart_kernel<<<1, 64, 0, stream>>>(partial, nb);
  chunkscan_kernel<<<nb, 64, 0, stream>>>(deg, partial, off, N);
  scatter_kernel<<<(E + 255) / 256, 256, 0, stream>>>(ei, off, cursor, eperm, sperm, E);

  float* xbuf = (float*)d_out;
  const float* xc = x_in;
  const int agg_blocks = (N + 7) / 8;
  const int mlp_blocks = (N + ROWS - 1) / ROWS;

  for (int c = 0; c < C; ++c) {
    agg_h_kernel<<<agg_blocks, 256, 0, stream>>>(xc, ea, off, eperm, sperm, eps + c, h, N);
    mlp_bn_kernel<<<mlp_blocks, 256, 0, stream>>>(
        xc, h,
        W1 + (size_t)c * D * D, b1 + (size_t)c * D,
        W2 + (size_t)c * D * D, b2 + (size_t)c * D,
        masks + (size_t)c * N,
        gamma + (size_t)c * D, beta + (size_t)c * D,
        rmean + (size_t)c * D, rvar + (size_t)c * D,
        x_in, xbuf, N, (c == C - 1) ? 1 : 0);
    xc = xbuf;
  }
}

// Round 3
// 885.834 us; speedup vs baseline: 5.6213x; 1.2891x over previous
//
#include <hip/hip_runtime.h>
#include <cstddef>

#define D 128
#define D4 32
#define CHUNK 1024
#define LDP 132   // padded LDS row stride in floats (132*4B = 528B, 16B-aligned)
#define BM 64     // rows per MLP block (4 waves x 16)

typedef __attribute__((ext_vector_type(8))) short s16x8;
typedef __attribute__((ext_vector_type(4))) float f32x4;

__device__ __forceinline__ unsigned short f2bf(float f) {
  unsigned u = __builtin_bit_cast(unsigned, f);
  u += 0x7FFFu + ((u >> 16) & 1u);
  return (unsigned short)(u >> 16);
}
__device__ __forceinline__ float bf2f(unsigned short h) {
  unsigned u = ((unsigned)h) << 16;
  return __builtin_bit_cast(float, u);
}

// ---------------- CSR build (once per call) ----------------
__global__ __launch_bounds__(256) void hist_kernel(const int* __restrict__ ei,
                                                   int* __restrict__ deg, int E) {
  int e = blockIdx.x * 256 + threadIdx.x;
  if (e < E) atomicAdd(&deg[ei[E + e]], 1);
}

__global__ __launch_bounds__(256) void partial_kernel(const int* __restrict__ deg,
                                                      int* __restrict__ partial, int N) {
  __shared__ int s[256];
  int base = blockIdx.x * CHUNK;
  int sum = 0;
  for (int j = threadIdx.x; j < CHUNK; j += 256) {
    int idx = base + j;
    sum += (idx < N) ? deg[idx] : 0;
  }
  s[threadIdx.x] = sum;
  __syncthreads();
  for (int ofs = 128; ofs > 0; ofs >>= 1) {
    if (threadIdx.x < ofs) s[threadIdx.x] += s[threadIdx.x + ofs];
    __syncthreads();
  }
  if (threadIdx.x == 0) partial[blockIdx.x] = s[0];
}

__global__ void scanpart_kernel(int* partial, int nb) {
  if (threadIdx.x == 0) {
    int run = 0;
    for (int i = 0; i < nb; ++i) { int v = partial[i]; partial[i] = run; run += v; }
  }
}

__global__ void chunkscan_kernel(const int* __restrict__ deg, const int* __restrict__ partial,
                                 int* __restrict__ off, int N) {
  if (threadIdx.x == 0) {
    int base = blockIdx.x * CHUNK;
    int run = partial[blockIdx.x];
    int end = min(base + CHUNK, N);
    for (int i = base; i < end; ++i) { off[i] = run; run += deg[i]; }
    if (end == N) off[N] = run;
  }
}

__global__ __launch_bounds__(256) void scatter_kernel(const int* __restrict__ ei,
                                                      const int* __restrict__ off,
                                                      int* __restrict__ cursor,
                                                      int* __restrict__ eperm,
                                                      int* __restrict__ sperm, int E) {
  int e = blockIdx.x * 256 + threadIdx.x;
  if (e < E) {
    int s = ei[e];
    int d = ei[E + e];
    int p = off[d] + atomicAdd(&cursor[d], 1);
    eperm[p] = e;
    sperm[p] = s;
  }
}

// ---------------- one-time: permuted bf16 edge_attr ----------------
__global__ __launch_bounds__(256) void conv_ea_kernel(const float* __restrict__ ea,
                                                      const int* __restrict__ eperm,
                                                      unsigned short* __restrict__ eap, int E) {
  int idx = blockIdx.x * 256 + threadIdx.x;
  int lane = idx & 31;
  int i = idx >> 5;
  if (i >= E) return;
  int e = eperm[i];
  float4 v = *reinterpret_cast<const float4*>(ea + (size_t)e * D + lane * 4);
  ushort4 o;
  o.x = f2bf(v.x); o.y = f2bf(v.y); o.z = f2bf(v.z); o.w = f2bf(v.w);
  *reinterpret_cast<ushort4*>(eap + (size_t)i * D + lane * 4) = o;
}

// ---------------- one-time: pack weights into B-fragment order, hi/lo bf16 ----------------
// layout per layer: [w1hi | w1lo | w2hi | w2lo], each D*D shorts.
// slot t = (ct*4+ks)*64 + l holds 8 shorts: W[ks*32+(l>>4)*8+i][ct*16+(l&15)]
__global__ void pack_w_kernel(const float* __restrict__ W1, const float* __restrict__ W2,
                              unsigned short* __restrict__ pk) {
  int c = blockIdx.x;
  const float* Ws[2] = {W1 + (size_t)c * D * D, W2 + (size_t)c * D * D};
  unsigned short* base = pk + (size_t)c * 4 * D * D;
  for (int t = threadIdx.x; t < 2048; t += blockDim.x) {
    int ct = t >> 8, ks = (t >> 6) & 3, l = t & 63;
    int col = ct * 16 + (l & 15);
    int krow = ks * 32 + ((l >> 4) & 3) * 8;
    for (int w = 0; w < 2; ++w) {
      unsigned short* hi = base + (size_t)w * 2 * D * D;
      unsigned short* lo = hi + D * D;
      const float* W = Ws[w];
      for (int i = 0; i < 8; ++i) {
        float v = W[(size_t)(krow + i) * D + col];
        unsigned short hb = f2bf(v);
        hi[(size_t)t * 8 + i] = hb;
        lo[(size_t)t * 8 + i] = f2bf(v - bf2f(hb));
      }
    }
  }
}

// ---------------- per-layer: gather-aggregate, fused h = (1+eps)x + agg ----------------
template <int USE16>
__global__ __launch_bounds__(256) void agg_h_kernel(
    const float* __restrict__ x, const float* __restrict__ ea,
    const unsigned short* __restrict__ eap,
    const int* __restrict__ off, const int* __restrict__ eperm,
    const int* __restrict__ sperm, const float* __restrict__ epsp,
    float* __restrict__ h, int N) {
  int row = blockIdx.x * 8 + (threadIdx.x >> 5);
  int lane = threadIdx.x & 31;
  if (row >= N) return;
  int beg = off[row], end = off[row + 1];
  float4 acc = make_float4(0.f, 0.f, 0.f, 0.f);
  for (int i = beg; i < end; ++i) {
    int s = sperm[i];
    float4 xv = *reinterpret_cast<const float4*>(x + (size_t)s * D + lane * 4);
    float4 ev;
    if (USE16) {
      ushort4 e4 = *reinterpret_cast<const ushort4*>(eap + (size_t)i * D + lane * 4);
      ev.x = bf2f(e4.x); ev.y = bf2f(e4.y); ev.z = bf2f(e4.z); ev.w = bf2f(e4.w);
    } else {
      int e = eperm[i];
      ev = *reinterpret_cast<const float4*>(ea + (size_t)e * D + lane * 4);
    }
    acc.x += fmaxf(xv.x + ev.x, 0.f);
    acc.y += fmaxf(xv.y + ev.y, 0.f);
    acc.z += fmaxf(xv.z + ev.z, 0.f);
    acc.w += fmaxf(xv.w + ev.w, 0.f);
  }
  float one_eps = 1.0f + epsp[0];
  float4 xd = *reinterpret_cast<const float4*>(x + (size_t)row * D + lane * 4);
  float4 hv;
  hv.x = fmaf(one_eps, xd.x, acc.x);
  hv.y = fmaf(one_eps, xd.y, acc.y);
  hv.z = fmaf(one_eps, xd.z, acc.z);
  hv.w = fmaf(one_eps, xd.w, acc.w);
  *reinterpret_cast<float4*>(h + (size_t)row * D + lane * 4) = hv;
}

// ---------------- MLP (split-bf16 MFMA) + mask residual + BN (+ final relu/residual) ----------------
__global__ __launch_bounds__(256) void mlp_bn_kernel(
    const float* __restrict__ x, const float* __restrict__ h,
    const unsigned short* __restrict__ wpk,   // this layer: w1hi|w1lo|w2hi|w2lo
    const float* __restrict__ b1, const float* __restrict__ b2,
    const float* __restrict__ mask,
    const float* __restrict__ gamma, const float* __restrict__ beta,
    const float* __restrict__ rmean, const float* __restrict__ rvar,
    const float* __restrict__ x_in, float* __restrict__ out,
    int N, int is_last) {
  __shared__ float hs[BM * LDP];  // 33.8 KB
  const int tid = threadIdx.x;
  const int r0 = blockIdx.x * BM;

  // stage h tile (fp32), coalesced
  for (int j = tid; j < BM * D4; j += 256) {
    int row = j >> 5, c4 = j & 31;
    int gr = r0 + row;
    float4 v = make_float4(0.f, 0.f, 0.f, 0.f);
    if (gr < N) v = *reinterpret_cast<const float4*>(h + (size_t)gr * D + c4 * 4);
    *reinterpret_cast<float4*>(hs + row * LDP + c4 * 4) = v;
  }
  __syncthreads();

  const int l = tid & 63;
  const int wave = tid >> 6;
  const int cl = l & 15;
  const int kq = l >> 4;                 // 0..3
  const int wr = wave * 16 + cl;         // LDS row this lane reads for A frags

  s16x8 ahi[4], alo[4];
#define LOAD_A_FRAGS()                                                   \
  _Pragma("unroll")                                                      \
  for (int ks = 0; ks < 4; ++ks) {                                       \
    const float* p = hs + wr * LDP + ks * 32 + kq * 8;                   \
    float4 v0 = *reinterpret_cast<const float4*>(p);                     \
    float4 v1 = *reinterpret_cast<const float4*>(p + 4);                 \
    float vv[8] = {v0.x, v0.y, v0.z, v0.w, v1.x, v1.y, v1.z, v1.w};      \
    s16x8 hi8, lo8;                                                      \
    _Pragma("unroll")                                                    \
    for (int i = 0; i < 8; ++i) {                                        \
      unsigned short hb = f2bf(vv[i]);                                   \
      hi8[i] = (short)hb;                                                \
      lo8[i] = (short)f2bf(vv[i] - bf2f(hb));                            \
    }                                                                    \
    ahi[ks] = hi8;                                                       \
    alo[ks] = lo8;                                                       \
  }

  // ---- GEMM1: T = relu(h @ W1 + b1) ----
  LOAD_A_FRAGS();
  {
    const s16x8* w1h = reinterpret_cast<const s16x8*>(wpk);
    const s16x8* w1l = reinterpret_cast<const s16x8*>(wpk + D * D);
#pragma unroll
    for (int ct = 0; ct < 8; ++ct) {
      f32x4 a = {0.f, 0.f, 0.f, 0.f};
#pragma unroll
      for (int ks = 0; ks < 4; ++ks) {
        s16x8 bh = w1h[(ct * 4 + ks) * 64 + l];
        s16x8 bl = w1l[(ct * 4 + ks) * 64 + l];
        a = __builtin_amdgcn_mfma_f32_16x16x32_bf16(ahi[ks], bh, a, 0, 0, 0);
        a = __builtin_amdgcn_mfma_f32_16x16x32_bf16(alo[ks], bh, a, 0, 0, 0);
        a = __builtin_amdgcn_mfma_f32_16x16x32_bf16(ahi[ks], bl, a, 0, 0, 0);
      }
      float bv = b1[ct * 16 + cl];
      // D row (within wave tile) = kq*4+i, col = ct*16+cl. Own-wave rows only.
#pragma unroll
      for (int i = 0; i < 4; ++i)
        hs[(wave * 16 + kq * 4 + i) * LDP + ct * 16 + cl] = fmaxf(a[i] + bv, 0.f);
    }
  }
  __builtin_amdgcn_sched_barrier(0);

  // ---- GEMM2: Y = T @ W2 ----
  LOAD_A_FRAGS();
  {
    const s16x8* w2h = reinterpret_cast<const s16x8*>(wpk + 2 * D * D);
    const s16x8* w2l = reinterpret_cast<const s16x8*>(wpk + 3 * D * D);
#pragma unroll
    for (int ct = 0; ct < 8; ++ct) {
      f32x4 a = {0.f, 0.f, 0.f, 0.f};
#pragma unroll
      for (int ks = 0; ks < 4; ++ks) {
        s16x8 bh = w2h[(ct * 4 + ks) * 64 + l];
        s16x8 bl = w2l[(ct * 4 + ks) * 64 + l];
        a = __builtin_amdgcn_mfma_f32_16x16x32_bf16(ahi[ks], bh, a, 0, 0, 0);
        a = __builtin_amdgcn_mfma_f32_16x16x32_bf16(alo[ks], bh, a, 0, 0, 0);
        a = __builtin_amdgcn_mfma_f32_16x16x32_bf16(ahi[ks], bl, a, 0, 0, 0);
      }
#pragma unroll
      for (int i = 0; i < 4; ++i)
        hs[(wave * 16 + kq * 4 + i) * LDP + ct * 16 + cl] = a[i];
    }
  }
  __syncthreads();

  // ---- epilogue: v = mask*(Y+b2) + x ; BN ; maybe final relu + outer residual ----
  for (int j = tid; j < BM * D4; j += 256) {
    int row = j >> 5, c4 = j & 31;
    int gr = r0 + row;
    if (gr >= N) continue;
    float4 yv = *reinterpret_cast<const float4*>(hs + row * LDP + c4 * 4);
    float4 b2v = reinterpret_cast<const float4*>(b2)[c4];
    float4 gv  = reinterpret_cast<const float4*>(gamma)[c4];
    float4 bv  = reinterpret_cast<const float4*>(beta)[c4];
    float4 rmv = reinterpret_cast<const float4*>(rmean)[c4];
    float4 rvv = reinterpret_cast<const float4*>(rvar)[c4];
    float4 sc;
    sc.x = gv.x * rsqrtf(rvv.x + 1e-5f);
    sc.y = gv.y * rsqrtf(rvv.y + 1e-5f);
    sc.z = gv.z * rsqrtf(rvv.z + 1e-5f);
    sc.w = gv.w * rsqrtf(rvv.w + 1e-5f);
    float mk = mask[gr];
    float4 xv = *reinterpret_cast<const float4*>(x + (size_t)gr * D + c4 * 4);
    float4 v;
    v.x = fmaf(mk, yv.x + b2v.x, xv.x);
    v.y = fmaf(mk, yv.y + b2v.y, xv.y);
    v.z = fmaf(mk, yv.z + b2v.z, xv.z);
    v.w = fmaf(mk, yv.w + b2v.w, xv.w);
    v.x = fmaf(v.x - rmv.x, sc.x, bv.x);
    v.y = fmaf(v.y - rmv.y, sc.y, bv.y);
    v.z = fmaf(v.z - rmv.z, sc.z, bv.z);
    v.w = fmaf(v.w - rmv.w, sc.w, bv.w);
    if (is_last) {
      float4 xi = *reinterpret_cast<const float4*>(x_in + (size_t)gr * D + c4 * 4);
      v.x = xi.x + fmaxf(v.x, 0.f);
      v.y = xi.y + fmaxf(v.y, 0.f);
      v.z = xi.z + fmaxf(v.z, 0.f);
      v.w = xi.w + fmaxf(v.w, 0.f);
    }
    *reinterpret_cast<float4*>(out + (size_t)gr * D + c4 * 4) = v;
  }
}

static inline char* align_up(char* p, size_t a) {
  return (char*)(((size_t)p + a - 1) & ~(a - 1));
}

extern "C" void kernel_launch(void* const* d_in, const int* in_sizes, int n_in,
                              void* d_out, int out_size, void* d_ws, size_t ws_size,
                              hipStream_t stream) {
  const float* x_in  = (const float*)d_in[0];
  const int*   ei    = (const int*)d_in[1];
  const float* ea    = (const float*)d_in[2];
  const float* masks = (const float*)d_in[3];
  const float* W1    = (const float*)d_in[4];
  const float* b1    = (const float*)d_in[5];
  const float* W2    = (const float*)d_in[6];
  const float* b2    = (const float*)d_in[7];
  const float* eps   = (const float*)d_in[8];
  const float* gamma = (const float*)d_in[9];
  const float* beta  = (const float*)d_in[10];
  const float* rmean = (const float*)d_in[11];
  const float* rvar  = (const float*)d_in[12];
  const int N = in_sizes[0] / D;
  const int E = in_sizes[1] / 2;
  const int C = in_sizes[8];
  const int nb = (N + CHUNK - 1) / CHUNK;

  // workspace layout
  char* w = (char*)d_ws;
  float* h     = (float*)w;  w += (size_t)N * D * sizeof(float);
  int* deg     = (int*)w;    w += (size_t)N * sizeof(int);
  int* off     = (int*)w;    w += (size_t)(N + 1) * sizeof(int);
  int* cursor  = (int*)w;    w += (size_t)N * sizeof(int);
  int* partial = (int*)w;    w += (size_t)(nb + 1) * sizeof(int);
  int* eperm   = (int*)w;    w += (size_t)E * sizeof(int);
  int* sperm   = (int*)w;    w += (size_t)E * sizeof(int);
  w = align_up(w, 64);
  unsigned short* wpk = (unsigned short*)w;  w += (size_t)C * 4 * D * D * sizeof(unsigned short);
  w = align_up(w, 64);
  unsigned short* eap = (unsigned short*)w;
  const int use16 = ((w - (char*)d_ws) + (size_t)E * D * sizeof(unsigned short)) <= ws_size;

  // ---- build CSR + packed weights (edge_index / weights are layer-loop invariant) ----
  hipMemsetAsync(deg, 0, (size_t)N * sizeof(int), stream);
  hipMemsetAsync(cursor, 0, (size_t)N * sizeof(int), stream);
  hist_kernel<<<(E + 255) / 256, 256, 0, stream>>>(ei, deg, E);
  partial_kernel<<<nb, 256, 0, stream>>>(deg, partial, N);
  scanpart_kernel<<<1, 64, 0, stream>>>(partial, nb);
  chunkscan_kernel<<<nb, 64, 0, stream>>>(deg, partial, off, N);
  scatter_kernel<<<(E + 255) / 256, 256, 0, stream>>>(ei, off, cursor, eperm, sperm, E);
  pack_w_kernel<<<C, 256, 0, stream>>>(W1, W2, wpk);
  if (use16) conv_ea_kernel<<<(E + 7) / 8, 256, 0, stream>>>(ea, eperm, eap, E);

  float* xbuf = (float*)d_out;
  const float* xc = x_in;
  const int agg_blocks = (N + 7) / 8;
  const int mlp_blocks = (N + BM - 1) / BM;

  for (int c = 0; c < C; ++c) {
    if (use16)
      agg_h_kernel<1><<<agg_blocks, 256, 0, stream>>>(xc, ea, eap, off, eperm, sperm, eps + c, h, N);
    else
      agg_h_kernel<0><<<agg_blocks, 256, 0, stream>>>(xc, ea, eap, off, eperm, sperm, eps + c, h, N);
    mlp_bn_kernel<<<mlp_blocks, 256, 0, stream>>>(
        xc, h,
        wpk + (size_t)c * 4 * D * D,
        b1 + (size_t)c * D, b2 + (size_t)c * D,
        masks + (size_t)c * N,
        gamma + (size_t)c * D, beta + (size_t)c * D,
        rmean + (size_t)c * D, rvar + (size_t)c * D,
        x_in, xbuf, N, (c == C - 1) ? 1 : 0);
    xc = xbuf;
  }
}

// Round 4
// 794.349 us; speedup vs baseline: 6.2687x; 1.1152x over previous
//
#include <hip/hip_runtime.h>
#include <cstddef>

#define D 128
#define CHUNK 1024
#define BM 64        // rows per layer block (4 waves x 16)
#define LDS 136      // LDS row stride in shorts (272B, 16B-aligned, 2-way-bank-free)
#define LDPF 132     // LDS row stride in floats for epilogue staging

typedef __attribute__((ext_vector_type(8))) short s16x8;
typedef __attribute__((ext_vector_type(4))) float f32x4;

__device__ __forceinline__ unsigned short f2bf(float f) {
  unsigned u = __builtin_bit_cast(unsigned, f);
  u += 0x7FFFu + ((u >> 16) & 1u);
  return (unsigned short)(u >> 16);
}
__device__ __forceinline__ float bf2f(unsigned short h) {
  unsigned u = ((unsigned)h) << 16;
  return __builtin_bit_cast(float, u);
}

// ---------------- CSR build (once per call) ----------------
__global__ __launch_bounds__(256) void hist_kernel(const int* __restrict__ ei,
                                                   int* __restrict__ deg, int E) {
  int e = blockIdx.x * 256 + threadIdx.x;
  if (e < E) atomicAdd(&deg[ei[E + e]], 1);
}

__global__ __launch_bounds__(256) void partial_kernel(const int* __restrict__ deg,
                                                      int* __restrict__ partial, int N) {
  __shared__ int s[256];
  int base = blockIdx.x * CHUNK;
  int sum = 0;
  for (int j = threadIdx.x; j < CHUNK; j += 256) {
    int idx = base + j;
    sum += (idx < N) ? deg[idx] : 0;
  }
  s[threadIdx.x] = sum;
  __syncthreads();
  for (int ofs = 128; ofs > 0; ofs >>= 1) {
    if (threadIdx.x < ofs) s[threadIdx.x] += s[threadIdx.x + ofs];
    __syncthreads();
  }
  if (threadIdx.x == 0) partial[blockIdx.x] = s[0];
}

// exclusive scan of partial[0..nb), nb <= 1024, single block
__global__ __launch_bounds__(1024) void scanpart_kernel(int* partial, int nb) {
  __shared__ int s[1024];
  int tid = threadIdx.x;
  int v = (tid < nb) ? partial[tid] : 0;
  s[tid] = v;
  __syncthreads();
  for (int o = 1; o < 1024; o <<= 1) {
    int t = (tid >= o) ? s[tid - o] : 0;
    __syncthreads();
    s[tid] += t;
    __syncthreads();
  }
  if (tid < nb) partial[tid] = s[tid] - v;
}

// per-chunk parallel scan: 256 threads x 4 elems = 1024
__global__ __launch_bounds__(256) void chunkscan_kernel(const int* __restrict__ deg,
                                                        const int* __restrict__ partial,
                                                        int* __restrict__ off, int N) {
  __shared__ int ws[4];
  int base = blockIdx.x * CHUNK;
  int i0 = base + threadIdx.x * 4;
  int d[4];
  int s = 0;
#pragma unroll
  for (int k = 0; k < 4; ++k) {
    d[k] = (i0 + k < N) ? deg[i0 + k] : 0;
    s += d[k];
  }
  int lane = threadIdx.x & 63;
  int incl = s;
  for (int o = 1; o < 64; o <<= 1) {
    int v = __shfl_up(incl, o, 64);
    if (lane >= o) incl += v;
  }
  int wave = threadIdx.x >> 6;
  if (lane == 63) ws[wave] = incl;
  __syncthreads();
  int wofs = 0;
  for (int w = 0; w < wave; ++w) wofs += ws[w];
  int run = partial[blockIdx.x] + wofs + (incl - s);
#pragma unroll
  for (int k = 0; k < 4; ++k) {
    int idx = i0 + k;
    if (idx < N) {
      off[idx] = run;
      run += d[k];
      if (idx == N - 1) off[N] = run;
    }
  }
}

// scatter + bf16 convert fused: half-wave per edge, ea read is sequential
__global__ __launch_bounds__(256) void scatter_conv_kernel(
    const int* __restrict__ ei, const float* __restrict__ ea,
    const int* __restrict__ off, int* __restrict__ cursor,
    int* __restrict__ sperm, unsigned short* __restrict__ eap, int E) {
  int t = blockIdx.x * 256 + threadIdx.x;
  int lane = t & 31;
  int e = t >> 5;
  if (e >= E) return;
  int p = 0;
  if (lane == 0) {
    int dnode = ei[E + e];
    p = off[dnode] + atomicAdd(&cursor[dnode], 1);
    sperm[p] = ei[e];
  }
  p = __shfl(p, 0, 32);
  float4 v = *reinterpret_cast<const float4*>(ea + (size_t)e * D + lane * 4);
  ushort4 o;
  o.x = f2bf(v.x); o.y = f2bf(v.y); o.z = f2bf(v.z); o.w = f2bf(v.w);
  *reinterpret_cast<ushort4*>(eap + (size_t)p * D + lane * 4) = o;
}

// ---------------- one-time: pack weights into B-fragment order, hi/lo bf16 ----------------
// layout per layer: [w1hi | w1lo | w2hi | w2lo], each D*D shorts.
// slot t = (ct*4+ks)*64 + l holds 8 shorts: W[ks*32+(l>>4)*8+i][ct*16+(l&15)]
__global__ void pack_w_kernel(const float* __restrict__ W1, const float* __restrict__ W2,
                              unsigned short* __restrict__ pk) {
  int c = blockIdx.x;
  const float* Ws[2] = {W1 + (size_t)c * D * D, W2 + (size_t)c * D * D};
  unsigned short* base = pk + (size_t)c * 4 * D * D;
  for (int t = threadIdx.x; t < 2048; t += blockDim.x) {
    int ct = t >> 8, ks = (t >> 6) & 3, l = t & 63;
    int col = ct * 16 + (l & 15);
    int krow = ks * 32 + ((l >> 4) & 3) * 8;
    for (int w = 0; w < 2; ++w) {
      unsigned short* hi = base + (size_t)w * 2 * D * D;
      unsigned short* lo = hi + D * D;
      const float* W = Ws[w];
      for (int i = 0; i < 8; ++i) {
        float v = W[(size_t)(krow + i) * D + col];
        unsigned short hb = f2bf(v);
        hi[(size_t)t * 8 + i] = hb;
        lo[(size_t)t * 8 + i] = f2bf(v - bf2f(hb));
      }
    }
  }
}

// ---------------- fused per-layer kernel: gather-agg + MLP + mask/BN epilogue ----------------
__global__ __launch_bounds__(256) void layer_kernel(
    const float* __restrict__ x, const unsigned short* __restrict__ eap,
    const int* __restrict__ off, const int* __restrict__ sperm,
    const float* __restrict__ epsp,
    const unsigned short* __restrict__ wpk,   // w1hi|w1lo|w2hi|w2lo
    const float* __restrict__ b1, const float* __restrict__ b2,
    const float* __restrict__ mask,
    const float* __restrict__ gamma, const float* __restrict__ beta,
    const float* __restrict__ rmean, const float* __restrict__ rvar,
    const float* __restrict__ x_in, float* __restrict__ out,
    int N, int is_last) {
  __shared__ __align__(16) char smem[3 * BM * LDS * 2];  // 52224 B
  unsigned short* h_hi = reinterpret_cast<unsigned short*>(smem);
  unsigned short* h_lo = h_hi + BM * LDS;
  unsigned short* t_hi = h_lo + BM * LDS;
  float* ys = reinterpret_cast<float*>(smem);  // reused after barrier for epilogue staging

  const int tid = threadIdx.x;
  const int r0 = blockIdx.x * BM;
  const float one_eps = 1.0f + epsp[0];

  // ---- phase 1: gather-aggregate, 16 quarter-wave rows concurrently ----
  {
    const int qw = tid >> 4;        // 0..15
    const int l16 = tid & 15;       // 8 floats per lane
#pragma unroll
    for (int it = 0; it < 4; ++it) {
      int row = it * 16 + qw;
      int gr = r0 + row;
      if (gr >= N) continue;
      int beg = off[gr], end = off[gr + 1];
      float4 a0 = make_float4(0.f, 0.f, 0.f, 0.f);
      float4 a1 = make_float4(0.f, 0.f, 0.f, 0.f);
      for (int i = beg; i < end; ++i) {
        int s = sperm[i];
        const float* xp = x + (size_t)s * D + l16 * 8;
        float4 xv0 = *reinterpret_cast<const float4*>(xp);
        float4 xv1 = *reinterpret_cast<const float4*>(xp + 4);
        uint4 ev = *reinterpret_cast<const uint4*>(eap + (size_t)i * D + l16 * 8);
        a0.x += fmaxf(xv0.x + bf2f((unsigned short)(ev.x & 0xffff)), 0.f);
        a0.y += fmaxf(xv0.y + bf2f((unsigned short)(ev.x >> 16)), 0.f);
        a0.z += fmaxf(xv0.z + bf2f((unsigned short)(ev.y & 0xffff)), 0.f);
        a0.w += fmaxf(xv0.w + bf2f((unsigned short)(ev.y >> 16)), 0.f);
        a1.x += fmaxf(xv1.x + bf2f((unsigned short)(ev.z & 0xffff)), 0.f);
        a1.y += fmaxf(xv1.y + bf2f((unsigned short)(ev.z >> 16)), 0.f);
        a1.z += fmaxf(xv1.z + bf2f((unsigned short)(ev.w & 0xffff)), 0.f);
        a1.w += fmaxf(xv1.w + bf2f((unsigned short)(ev.w >> 16)), 0.f);
      }
      const float* xd = x + (size_t)gr * D + l16 * 8;
      float4 x0 = *reinterpret_cast<const float4*>(xd);
      float4 x1 = *reinterpret_cast<const float4*>(xd + 4);
      float hv[8];
      hv[0] = fmaf(one_eps, x0.x, a0.x); hv[1] = fmaf(one_eps, x0.y, a0.y);
      hv[2] = fmaf(one_eps, x0.z, a0.z); hv[3] = fmaf(one_eps, x0.w, a0.w);
      hv[4] = fmaf(one_eps, x1.x, a1.x); hv[5] = fmaf(one_eps, x1.y, a1.y);
      hv[6] = fmaf(one_eps, x1.z, a1.z); hv[7] = fmaf(one_eps, x1.w, a1.w);
      ushort4 hi0, hi1, lo0, lo1;
      unsigned short hb;
#define CV(dst_hi, dst_lo, v) hb = f2bf(v); dst_hi = hb; dst_lo = f2bf((v) - bf2f(hb));
      CV(hi0.x, lo0.x, hv[0]) CV(hi0.y, lo0.y, hv[1]) CV(hi0.z, lo0.z, hv[2]) CV(hi0.w, lo0.w, hv[3])
      CV(hi1.x, lo1.x, hv[4]) CV(hi1.y, lo1.y, hv[5]) CV(hi1.z, lo1.z, hv[6]) CV(hi1.w, lo1.w, hv[7])
#undef CV
      unsigned short* ph = h_hi + row * LDS + l16 * 8;
      unsigned short* pl = h_lo + row * LDS + l16 * 8;
      *reinterpret_cast<ushort4*>(ph) = hi0;
      *reinterpret_cast<ushort4*>(ph + 4) = hi1;
      *reinterpret_cast<ushort4*>(pl) = lo0;
      *reinterpret_cast<ushort4*>(pl + 4) = lo1;
    }
  }
  __syncthreads();

  const int l = tid & 63;
  const int wave = tid >> 6;
  const int cl = l & 15;
  const int kq = l >> 4;                 // 0..3
  const int wr = wave * 16 + cl;         // own-wave LDS row for A frags

  // ---- GEMM1: T = relu(h @ W1 + b1), 3-term split ----
  {
    s16x8 ahi[4], alo[4];
#pragma unroll
    for (int ks = 0; ks < 4; ++ks) {
      ahi[ks] = *reinterpret_cast<const s16x8*>(h_hi + wr * LDS + ks * 32 + kq * 8);
      alo[ks] = *reinterpret_cast<const s16x8*>(h_lo + wr * LDS + ks * 32 + kq * 8);
    }
    const s16x8* w1h = reinterpret_cast<const s16x8*>(wpk);
    const s16x8* w1l = reinterpret_cast<const s16x8*>(wpk + D * D);
#pragma unroll
    for (int ct = 0; ct < 8; ++ct) {
      f32x4 a = {0.f, 0.f, 0.f, 0.f};
#pragma unroll
      for (int ks = 0; ks < 4; ++ks) {
        s16x8 bh = w1h[(ct * 4 + ks) * 64 + l];
        s16x8 bl = w1l[(ct * 4 + ks) * 64 + l];
        a = __builtin_amdgcn_mfma_f32_16x16x32_bf16(ahi[ks], bh, a, 0, 0, 0);
        a = __builtin_amdgcn_mfma_f32_16x16x32_bf16(alo[ks], bh, a, 0, 0, 0);
        a = __builtin_amdgcn_mfma_f32_16x16x32_bf16(ahi[ks], bl, a, 0, 0, 0);
      }
      float bv = b1[ct * 16 + cl];
#pragma unroll
      for (int i = 0; i < 4; ++i)
        t_hi[(wave * 16 + kq * 4 + i) * LDS + ct * 16 + cl] = f2bf(fmaxf(a[i] + bv, 0.f));
    }
  }
  __builtin_amdgcn_sched_barrier(0);
  __syncthreads();  // all h reads done -> ys region reusable after GEMM2 math

  // ---- GEMM2: Y = T @ W2, 2-term split (B-side hi/lo) ----
  {
    s16x8 thi[4];
#pragma unroll
    for (int ks = 0; ks < 4; ++ks)
      thi[ks] = *reinterpret_cast<const s16x8*>(t_hi + wr * LDS + ks * 32 + kq * 8);
    const s16x8* w2h = reinterpret_cast<const s16x8*>(wpk + 2 * D * D);
    const s16x8* w2l = reinterpret_cast<const s16x8*>(wpk + 3 * D * D);
#pragma unroll
    for (int ct = 0; ct < 8; ++ct) {
      f32x4 a = {0.f, 0.f, 0.f, 0.f};
#pragma unroll
      for (int ks = 0; ks < 4; ++ks) {
        s16x8 bh = w2h[(ct * 4 + ks) * 64 + l];
        s16x8 bl = w2l[(ct * 4 + ks) * 64 + l];
        a = __builtin_amdgcn_mfma_f32_16x16x32_bf16(thi[ks], bh, a, 0, 0, 0);
        a = __builtin_amdgcn_mfma_f32_16x16x32_bf16(thi[ks], bl, a, 0, 0, 0);
      }
#pragma unroll
      for (int i = 0; i < 4; ++i)
        ys[(wave * 16 + kq * 4 + i) * LDPF + ct * 16 + cl] = a[i];
    }
  }
  __syncthreads();

  // ---- epilogue: v = mask*(Y+b2) + x ; BN ; maybe final relu + outer residual ----
  for (int j = tid; j < BM * 32; j += 256) {
    int row = j >> 5, c4 = j & 31;
    int gr = r0 + row;
    if (gr >= N) continue;
    float4 yv = *reinterpret_cast<const float4*>(ys + row * LDPF + c4 * 4);
    float4 b2v = reinterpret_cast<const float4*>(b2)[c4];
    float4 gv  = reinterpret_cast<const float4*>(gamma)[c4];
    float4 bv  = reinterpret_cast<const float4*>(beta)[c4];
    float4 rmv = reinterpret_cast<const float4*>(rmean)[c4];
    float4 rvv = reinterpret_cast<const float4*>(rvar)[c4];
    float4 sc;
    sc.x = gv.x * rsqrtf(rvv.x + 1e-5f);
    sc.y = gv.y * rsqrtf(rvv.y + 1e-5f);
    sc.z = gv.z * rsqrtf(rvv.z + 1e-5f);
    sc.w = gv.w * rsqrtf(rvv.w + 1e-5f);
    float mk = mask[gr];
    float4 xv = *reinterpret_cast<const float4*>(x + (size_t)gr * D + c4 * 4);
    float4 v;
    v.x = fmaf(mk, yv.x + b2v.x, xv.x);
    v.y = fmaf(mk, yv.y + b2v.y, xv.y);
    v.z = fmaf(mk, yv.z + b2v.z, xv.z);
    v.w = fmaf(mk, yv.w + b2v.w, xv.w);
    v.x = fmaf(v.x - rmv.x, sc.x, bv.x);
    v.y = fmaf(v.y - rmv.y, sc.y, bv.y);
    v.z = fmaf(v.z - rmv.z, sc.z, bv.z);
    v.w = fmaf(v.w - rmv.w, sc.w, bv.w);
    if (is_last) {
      float4 xi = *reinterpret_cast<const float4*>(x_in + (size_t)gr * D + c4 * 4);
      v.x = xi.x + fmaxf(v.x, 0.f);
      v.y = xi.y + fmaxf(v.y, 0.f);
      v.z = xi.z + fmaxf(v.z, 0.f);
      v.w = xi.w + fmaxf(v.w, 0.f);
    }
    *reinterpret_cast<float4*>(out + (size_t)gr * D + c4 * 4) = v;
  }
}

static inline char* align_up(char* p, size_t a) {
  return (char*)(((size_t)p + a - 1) & ~(a - 1));
}

extern "C" void kernel_launch(void* const* d_in, const int* in_sizes, int n_in,
                              void* d_out, int out_size, void* d_ws, size_t ws_size,
                              hipStream_t stream) {
  const float* x_in  = (const float*)d_in[0];
  const int*   ei    = (const int*)d_in[1];
  const float* ea    = (const float*)d_in[2];
  const float* masks = (const float*)d_in[3];
  const float* W1    = (const float*)d_in[4];
  const float* b1    = (const float*)d_in[5];
  const float* W2    = (const float*)d_in[6];
  const float* b2    = (const float*)d_in[7];
  const float* eps   = (const float*)d_in[8];
  const float* gamma = (const float*)d_in[9];
  const float* beta  = (const float*)d_in[10];
  const float* rmean = (const float*)d_in[11];
  const float* rvar  = (const float*)d_in[12];
  const int N = in_sizes[0] / D;
  const int E = in_sizes[1] / 2;
  const int C = in_sizes[8];
  const int nb = (N + CHUNK - 1) / CHUNK;

  // workspace layout
  char* w = (char*)d_ws;
  float* xalt  = (float*)w;  w += (size_t)N * D * sizeof(float);
  int* deg     = (int*)w;    w += (size_t)N * sizeof(int);
  int* off     = (int*)w;    w += (size_t)(N + 1) * sizeof(int);
  int* cursor  = (int*)w;    w += (size_t)N * sizeof(int);
  int* partial = (int*)w;    w += (size_t)(nb + 1) * sizeof(int);
  int* sperm   = (int*)w;    w += (size_t)E * sizeof(int);
  w = align_up(w, 64);
  unsigned short* wpk = (unsigned short*)w;  w += (size_t)C * 4 * D * D * sizeof(unsigned short);
  w = align_up(w, 64);
  unsigned short* eap = (unsigned short*)w;

  // ---- build CSR + permuted bf16 edge_attr + packed weights (loop-invariant) ----
  hipMemsetAsync(deg, 0, (size_t)N * sizeof(int), stream);
  hipMemsetAsync(cursor, 0, (size_t)N * sizeof(int), stream);
  hist_kernel<<<(E + 255) / 256, 256, 0, stream>>>(ei, deg, E);
  partial_kernel<<<nb, 256, 0, stream>>>(deg, partial, N);
  scanpart_kernel<<<1, 1024, 0, stream>>>(partial, nb);
  chunkscan_kernel<<<nb, 256, 0, stream>>>(deg, partial, off, N);
  scatter_conv_kernel<<<(E + 7) / 8, 256, 0, stream>>>(ei, ea, off, cursor, sperm, eap, E);
  pack_w_kernel<<<C, 256, 0, stream>>>(W1, W2, wpk);

  const int blocks = (N + BM - 1) / BM;
  const float* xc = x_in;
  for (int c = 0; c < C; ++c) {
    float* dst = (((C - 1 - c) & 1) == 0) ? (float*)d_out : xalt;
    layer_kernel<<<blocks, 256, 0, stream>>>(
        xc, eap, off, sperm, eps + c,
        wpk + (size_t)c * 4 * D * D,
        b1 + (size_t)c * D, b2 + (size_t)c * D,
        masks + (size_t)c * N,
        gamma + (size_t)c * D, beta + (size_t)c * D,
        rmean + (size_t)c * D, rvar + (size_t)c * D,
        x_in, dst, N, (c == C - 1) ? 1 : 0);
    xc = dst;
  }
}

// Round 5
// 778.127 us; speedup vs baseline: 6.3994x; 1.0208x over previous
//
#include <hip/hip_runtime.h>
#include <cstddef>

#define D 128
#define CHUNK 1024
#define BM 64        // rows per layer block (4 waves; 2M x 2N wave grid)
#define LDS 136      // LDS row stride in shorts (272B, 16B-aligned)
#define LDPF 132     // LDS row stride in floats for epilogue staging

typedef __attribute__((ext_vector_type(8))) short s16x8;
typedef __attribute__((ext_vector_type(4))) float f32x4;
typedef __attribute__((ext_vector_type(2))) float f32x2;

__device__ __forceinline__ unsigned short f2bf(float f) {
  unsigned u = __builtin_bit_cast(unsigned, f);
  u += 0x7FFFu + ((u >> 16) & 1u);
  return (unsigned short)(u >> 16);
}
__device__ __forceinline__ float bf2f(unsigned short h) {
  unsigned u = ((unsigned)h) << 16;
  return __builtin_bit_cast(float, u);
}
__device__ __forceinline__ unsigned f32x4_to_fp8(float4 v) {
  int r = __builtin_amdgcn_cvt_pk_fp8_f32(v.x, v.y, 0, false);
  r = __builtin_amdgcn_cvt_pk_fp8_f32(v.z, v.w, r, true);
  return (unsigned)r;
}
__device__ __forceinline__ void fp8x4_to_f32(unsigned u, float* o) {
  f32x2 lo = __builtin_amdgcn_cvt_pk_f32_fp8((int)u, false);
  f32x2 hi = __builtin_amdgcn_cvt_pk_f32_fp8((int)u, true);
  o[0] = lo[0]; o[1] = lo[1]; o[2] = hi[0]; o[3] = hi[1];
}

// ---------------- CSR build (once per call) ----------------
__global__ __launch_bounds__(256) void hist_kernel(const int* __restrict__ ei,
                                                   int* __restrict__ deg, int E) {
  int e = blockIdx.x * 256 + threadIdx.x;
  if (e < E) atomicAdd(&deg[ei[E + e]], 1);
}

__global__ __launch_bounds__(256) void partial_kernel(const int* __restrict__ deg,
                                                      int* __restrict__ partial, int N) {
  __shared__ int s[256];
  int base = blockIdx.x * CHUNK;
  int sum = 0;
  for (int j = threadIdx.x; j < CHUNK; j += 256) {
    int idx = base + j;
    sum += (idx < N) ? deg[idx] : 0;
  }
  s[threadIdx.x] = sum;
  __syncthreads();
  for (int ofs = 128; ofs > 0; ofs >>= 1) {
    if (threadIdx.x < ofs) s[threadIdx.x] += s[threadIdx.x + ofs];
    __syncthreads();
  }
  if (threadIdx.x == 0) partial[blockIdx.x] = s[0];
}

// exclusive scan of partial[0..nb), nb <= 1024, single block
__global__ __launch_bounds__(1024) void scanpart_kernel(int* partial, int nb) {
  __shared__ int s[1024];
  int tid = threadIdx.x;
  int v = (tid < nb) ? partial[tid] : 0;
  s[tid] = v;
  __syncthreads();
  for (int o = 1; o < 1024; o <<= 1) {
    int t = (tid >= o) ? s[tid - o] : 0;
    __syncthreads();
    s[tid] += t;
    __syncthreads();
  }
  if (tid < nb) partial[tid] = s[tid] - v;
}

// per-chunk parallel scan: 256 threads x 4 elems = 1024
__global__ __launch_bounds__(256) void chunkscan_kernel(const int* __restrict__ deg,
                                                        const int* __restrict__ partial,
                                                        int* __restrict__ off, int N) {
  __shared__ int ws[4];
  int base = blockIdx.x * CHUNK;
  int i0 = base + threadIdx.x * 4;
  int d[4];
  int s = 0;
#pragma unroll
  for (int k = 0; k < 4; ++k) {
    d[k] = (i0 + k < N) ? deg[i0 + k] : 0;
    s += d[k];
  }
  int lane = threadIdx.x & 63;
  int incl = s;
  for (int o = 1; o < 64; o <<= 1) {
    int v = __shfl_up(incl, o, 64);
    if (lane >= o) incl += v;
  }
  int wave = threadIdx.x >> 6;
  if (lane == 63) ws[wave] = incl;
  __syncthreads();
  int wofs = 0;
  for (int w = 0; w < wave; ++w) wofs += ws[w];
  int run = partial[blockIdx.x] + wofs + (incl - s);
#pragma unroll
  for (int k = 0; k < 4; ++k) {
    int idx = i0 + k;
    if (idx < N) {
      off[idx] = run;
      run += d[k];
      if (idx == N - 1) off[N] = run;
    }
  }
}

// scatter + fp8 convert fused: half-wave per edge, ea read is sequential
__global__ __launch_bounds__(256) void scatter_conv_kernel(
    const int* __restrict__ ei, const float* __restrict__ ea,
    const int* __restrict__ off, int* __restrict__ cursor,
    int* __restrict__ sperm, unsigned char* __restrict__ eap, int E) {
  int t = blockIdx.x * 256 + threadIdx.x;
  int lane = t & 31;
  int e = t >> 5;
  if (e >= E) return;
  int p = 0;
  if (lane == 0) {
    int dnode = ei[E + e];
    p = off[dnode] + atomicAdd(&cursor[dnode], 1);
    sperm[p] = ei[e];
  }
  p = __shfl(p, 0, 32);
  float4 v = *reinterpret_cast<const float4*>(ea + (size_t)e * D + lane * 4);
  reinterpret_cast<unsigned*>(eap)[(size_t)p * 32 + lane] = f32x4_to_fp8(v);
}

// ---------------- one-time: pack weights into B-fragment order, hi/lo bf16 ----------------
// layout per layer: [w1hi | w1lo | w2hi | w2lo], each D*D shorts.
// slot t = (ct*4+ks)*64 + l holds 8 shorts: W[ks*32+(l>>4)*8+i][ct*16+(l&15)]
__global__ void pack_w_kernel(const float* __restrict__ W1, const float* __restrict__ W2,
                              unsigned short* __restrict__ pk) {
  int c = blockIdx.x;
  const float* Ws[2] = {W1 + (size_t)c * D * D, W2 + (size_t)c * D * D};
  unsigned short* base = pk + (size_t)c * 4 * D * D;
  for (int t = threadIdx.x; t < 2048; t += blockDim.x) {
    int ct = t >> 8, ks = (t >> 6) & 3, l = t & 63;
    int col = ct * 16 + (l & 15);
    int krow = ks * 32 + ((l >> 4) & 3) * 8;
    for (int w = 0; w < 2; ++w) {
      unsigned short* hi = base + (size_t)w * 2 * D * D;
      unsigned short* lo = hi + D * D;
      const float* W = Ws[w];
      for (int i = 0; i < 8; ++i) {
        float v = W[(size_t)(krow + i) * D + col];
        unsigned short hb = f2bf(v);
        hi[(size_t)t * 8 + i] = hb;
        lo[(size_t)t * 8 + i] = f2bf(v - bf2f(hb));
      }
    }
  }
}

// ---------------- fused per-layer kernel: gather-agg + MLP + mask/BN epilogue ----------------
__global__ __launch_bounds__(256) void layer_kernel(
    const float* __restrict__ x, const unsigned char* __restrict__ eap,
    const int* __restrict__ off, const int* __restrict__ sperm,
    const float* __restrict__ epsp,
    const unsigned short* __restrict__ wpk,   // w1hi|w1lo|w2hi|w2lo
    const float* __restrict__ b1, const float* __restrict__ b2,
    const float* __restrict__ mask,
    const float* __restrict__ gamma, const float* __restrict__ beta,
    const float* __restrict__ rmean, const float* __restrict__ rvar,
    const float* __restrict__ x_in, float* __restrict__ out,
    int N, int is_last) {
  __shared__ __align__(16) char smem[3 * BM * LDS * 2];  // 52224 B
  unsigned short* h_hi = reinterpret_cast<unsigned short*>(smem);
  unsigned short* h_lo = h_hi + BM * LDS;
  unsigned short* t_hi = h_lo + BM * LDS;
  float* ys = reinterpret_cast<float*>(smem);  // reused after barrier for epilogue staging

  const int tid = threadIdx.x;
  const int r0 = blockIdx.x * BM;
  const float one_eps = 1.0f + epsp[0];

  // ---- phase 1: gather-aggregate, 16 quarter-wave rows concurrently ----
  {
    const int qw = tid >> 4;        // 0..15
    const int l16 = tid & 15;       // 8 floats per lane
#pragma unroll
    for (int it = 0; it < 4; ++it) {
      int row = it * 16 + qw;
      int gr = r0 + row;
      if (gr >= N) continue;
      int beg = off[gr], end = off[gr + 1];
      float4 a0 = make_float4(0.f, 0.f, 0.f, 0.f);
      float4 a1 = make_float4(0.f, 0.f, 0.f, 0.f);
      for (int i = beg; i < end; ++i) {
        int s = sperm[i];
        const float* xp = x + (size_t)s * D + l16 * 8;
        float4 xv0 = *reinterpret_cast<const float4*>(xp);
        float4 xv1 = *reinterpret_cast<const float4*>(xp + 4);
        uint2 eu = *reinterpret_cast<const uint2*>(eap + (size_t)i * D + l16 * 8);
        float ev[8];
        fp8x4_to_f32(eu.x, ev);
        fp8x4_to_f32(eu.y, ev + 4);
        a0.x += fmaxf(xv0.x + ev[0], 0.f);
        a0.y += fmaxf(xv0.y + ev[1], 0.f);
        a0.z += fmaxf(xv0.z + ev[2], 0.f);
        a0.w += fmaxf(xv0.w + ev[3], 0.f);
        a1.x += fmaxf(xv1.x + ev[4], 0.f);
        a1.y += fmaxf(xv1.y + ev[5], 0.f);
        a1.z += fmaxf(xv1.z + ev[6], 0.f);
        a1.w += fmaxf(xv1.w + ev[7], 0.f);
      }
      const float* xd = x + (size_t)gr * D + l16 * 8;
      float4 x0 = *reinterpret_cast<const float4*>(xd);
      float4 x1 = *reinterpret_cast<const float4*>(xd + 4);
      float hv[8];
      hv[0] = fmaf(one_eps, x0.x, a0.x); hv[1] = fmaf(one_eps, x0.y, a0.y);
      hv[2] = fmaf(one_eps, x0.z, a0.z); hv[3] = fmaf(one_eps, x0.w, a0.w);
      hv[4] = fmaf(one_eps, x1.x, a1.x); hv[5] = fmaf(one_eps, x1.y, a1.y);
      hv[6] = fmaf(one_eps, x1.z, a1.z); hv[7] = fmaf(one_eps, x1.w, a1.w);
      ushort4 hi0, hi1, lo0, lo1;
      unsigned short hb;
#define CV(dst_hi, dst_lo, v) hb = f2bf(v); dst_hi = hb; dst_lo = f2bf((v) - bf2f(hb));
      CV(hi0.x, lo0.x, hv[0]) CV(hi0.y, lo0.y, hv[1]) CV(hi0.z, lo0.z, hv[2]) CV(hi0.w, lo0.w, hv[3])
      CV(hi1.x, lo1.x, hv[4]) CV(hi1.y, lo1.y, hv[5]) CV(hi1.z, lo1.z, hv[6]) CV(hi1.w, lo1.w, hv[7])
#undef CV
      unsigned short* ph = h_hi + row * LDS + l16 * 8;
      unsigned short* pl = h_lo + row * LDS + l16 * 8;
      *reinterpret_cast<ushort4*>(ph) = hi0;
      *reinterpret_cast<ushort4*>(ph + 4) = hi1;
      *reinterpret_cast<ushort4*>(pl) = lo0;
      *reinterpret_cast<ushort4*>(pl + 4) = lo1;
    }
  }
  __syncthreads();

  const int l = tid & 63;
  const int wave = tid >> 6;
  const int wm = wave >> 1;              // row half (32 rows)
  const int wn = wave & 1;               // col half (64 cols)
  const int cl = l & 15;
  const int kq = l >> 4;                 // 0..3

  // ---- GEMM1: T = relu(h @ W1 + b1), 3-term split, 32x64 per wave ----
  {
    s16x8 ahi[2][4], alo[2][4];
#pragma unroll
    for (int rt = 0; rt < 2; ++rt) {
      int row = wm * 32 + rt * 16 + cl;
#pragma unroll
      for (int ks = 0; ks < 4; ++ks) {
        ahi[rt][ks] = *reinterpret_cast<const s16x8*>(h_hi + row * LDS + ks * 32 + kq * 8);
        alo[rt][ks] = *reinterpret_cast<const s16x8*>(h_lo + row * LDS + ks * 32 + kq * 8);
      }
    }
    const s16x8* w1h = reinterpret_cast<const s16x8*>(wpk);
    const s16x8* w1l = reinterpret_cast<const s16x8*>(wpk + D * D);
#pragma unroll
    for (int ct = 0; ct < 4; ++ct) {
      int gct = wn * 4 + ct;
      f32x4 a0 = {0.f, 0.f, 0.f, 0.f};
      f32x4 a1 = {0.f, 0.f, 0.f, 0.f};
#pragma unroll
      for (int ks = 0; ks < 4; ++ks) {
        s16x8 bh = w1h[(gct * 4 + ks) * 64 + l];
        s16x8 bl = w1l[(gct * 4 + ks) * 64 + l];
        a0 = __builtin_amdgcn_mfma_f32_16x16x32_bf16(ahi[0][ks], bh, a0, 0, 0, 0);
        a0 = __builtin_amdgcn_mfma_f32_16x16x32_bf16(alo[0][ks], bh, a0, 0, 0, 0);
        a0 = __builtin_amdgcn_mfma_f32_16x16x32_bf16(ahi[0][ks], bl, a0, 0, 0, 0);
        a1 = __builtin_amdgcn_mfma_f32_16x16x32_bf16(ahi[1][ks], bh, a1, 0, 0, 0);
        a1 = __builtin_amdgcn_mfma_f32_16x16x32_bf16(alo[1][ks], bh, a1, 0, 0, 0);
        a1 = __builtin_amdgcn_mfma_f32_16x16x32_bf16(ahi[1][ks], bl, a1, 0, 0, 0);
      }
      float bv = b1[gct * 16 + cl];
#pragma unroll
      for (int i = 0; i < 4; ++i) {
        t_hi[(wm * 32 + kq * 4 + i) * LDS + gct * 16 + cl] = f2bf(fmaxf(a0[i] + bv, 0.f));
        t_hi[(wm * 32 + 16 + kq * 4 + i) * LDS + gct * 16 + cl] = f2bf(fmaxf(a1[i] + bv, 0.f));
      }
    }
  }
  __builtin_amdgcn_sched_barrier(0);
  __syncthreads();  // all h reads done -> ys region reusable; T complete

  // ---- GEMM2: Y = T @ W2, 2-term split (B-side hi/lo) ----
  {
    s16x8 thi[2][4];
#pragma unroll
    for (int rt = 0; rt < 2; ++rt) {
      int row = wm * 32 + rt * 16 + cl;
#pragma unroll
      for (int ks = 0; ks < 4; ++ks)
        thi[rt][ks] = *reinterpret_cast<const s16x8*>(t_hi + row * LDS + ks * 32 + kq * 8);
    }
    const s16x8* w2h = reinterpret_cast<const s16x8*>(wpk + 2 * D * D);
    const s16x8* w2l = reinterpret_cast<const s16x8*>(wpk + 3 * D * D);
#pragma unroll
    for (int ct = 0; ct < 4; ++ct) {
      int gct = wn * 4 + ct;
      f32x4 a0 = {0.f, 0.f, 0.f, 0.f};
      f32x4 a1 = {0.f, 0.f, 0.f, 0.f};
#pragma unroll
      for (int ks = 0; ks < 4; ++ks) {
        s16x8 bh = w2h[(gct * 4 + ks) * 64 + l];
        s16x8 bl = w2l[(gct * 4 + ks) * 64 + l];
        a0 = __builtin_amdgcn_mfma_f32_16x16x32_bf16(thi[0][ks], bh, a0, 0, 0, 0);
        a0 = __builtin_amdgcn_mfma_f32_16x16x32_bf16(thi[0][ks], bl, a0, 0, 0, 0);
        a1 = __builtin_amdgcn_mfma_f32_16x16x32_bf16(thi[1][ks], bh, a1, 0, 0, 0);
        a1 = __builtin_amdgcn_mfma_f32_16x16x32_bf16(thi[1][ks], bl, a1, 0, 0, 0);
      }
#pragma unroll
      for (int i = 0; i < 4; ++i) {
        ys[(wm * 32 + kq * 4 + i) * LDPF + gct * 16 + cl] = a0[i];
        ys[(wm * 32 + 16 + kq * 4 + i) * LDPF + gct * 16 + cl] = a1[i];
      }
    }
  }
  __syncthreads();

  // ---- epilogue: v = mask*(Y+b2) + x ; BN ; maybe final relu + outer residual ----
  for (int j = tid; j < BM * 32; j += 256) {
    int row = j >> 5, c4 = j & 31;
    int gr = r0 + row;
    if (gr >= N) continue;
    float4 yv = *reinterpret_cast<const float4*>(ys + row * LDPF + c4 * 4);
    float4 b2v = reinterpret_cast<const float4*>(b2)[c4];
    float4 gv  = reinterpret_cast<const float4*>(gamma)[c4];
    float4 bv  = reinterpret_cast<const float4*>(beta)[c4];
    float4 rmv = reinterpret_cast<const float4*>(rmean)[c4];
    float4 rvv = reinterpret_cast<const float4*>(rvar)[c4];
    float4 sc;
    sc.x = gv.x * rsqrtf(rvv.x + 1e-5f);
    sc.y = gv.y * rsqrtf(rvv.y + 1e-5f);
    sc.z = gv.z * rsqrtf(rvv.z + 1e-5f);
    sc.w = gv.w * rsqrtf(rvv.w + 1e-5f);
    float mk = mask[gr];
    float4 xv = *reinterpret_cast<const float4*>(x + (size_t)gr * D + c4 * 4);
    float4 v;
    v.x = fmaf(mk, yv.x + b2v.x, xv.x);
    v.y = fmaf(mk, yv.y + b2v.y, xv.y);
    v.z = fmaf(mk, yv.z + b2v.z, xv.z);
    v.w = fmaf(mk, yv.w + b2v.w, xv.w);
    v.x = fmaf(v.x - rmv.x, sc.x, bv.x);
    v.y = fmaf(v.y - rmv.y, sc.y, bv.y);
    v.z = fmaf(v.z - rmv.z, sc.z, bv.z);
    v.w = fmaf(v.w - rmv.w, sc.w, bv.w);
    if (is_last) {
      float4 xi = *reinterpret_cast<const float4*>(x_in + (size_t)gr * D + c4 * 4);
      v.x = xi.x + fmaxf(v.x, 0.f);
      v.y = xi.y + fmaxf(v.y, 0.f);
      v.z = xi.z + fmaxf(v.z, 0.f);
      v.w = xi.w + fmaxf(v.w, 0.f);
    }
    *reinterpret_cast<float4*>(out + (size_t)gr * D + c4 * 4) = v;
  }
}

static inline char* align_up(char* p, size_t a) {
  return (char*)(((size_t)p + a - 1) & ~(a - 1));
}

extern "C" void kernel_launch(void* const* d_in, const int* in_sizes, int n_in,
                              void* d_out, int out_size, void* d_ws, size_t ws_size,
                              hipStream_t stream) {
  const float* x_in  = (const float*)d_in[0];
  const int*   ei    = (const int*)d_in[1];
  const float* ea    = (const float*)d_in[2];
  const float* masks = (const float*)d_in[3];
  const float* W1    = (const float*)d_in[4];
  const float* b1    = (const float*)d_in[5];
  const float* W2    = (const float*)d_in[6];
  const float* b2    = (const float*)d_in[7];
  const float* eps   = (const float*)d_in[8];
  const float* gamma = (const float*)d_in[9];
  const float* beta  = (const float*)d_in[10];
  const float* rmean = (const float*)d_in[11];
  const float* rvar  = (const float*)d_in[12];
  const int N = in_sizes[0] / D;
  const int E = in_sizes[1] / 2;
  const int C = in_sizes[8];
  const int nb = (N + CHUNK - 1) / CHUNK;

  // workspace layout
  char* w = (char*)d_ws;
  float* xalt  = (float*)w;  w += (size_t)N * D * sizeof(float);
  int* deg     = (int*)w;    w += (size_t)N * sizeof(int);
  int* off     = (int*)w;    w += (size_t)(N + 1) * sizeof(int);
  int* cursor  = (int*)w;    w += (size_t)N * sizeof(int);
  int* partial = (int*)w;    w += (size_t)(nb + 1) * sizeof(int);
  int* sperm   = (int*)w;    w += (size_t)E * sizeof(int);
  w = align_up(w, 128);
  unsigned short* wpk = (unsigned short*)w;  w += (size_t)C * 4 * D * D * sizeof(unsigned short);
  w = align_up(w, 128);
  unsigned char* eap = (unsigned char*)w;    // E * 128 bytes (fp8 e4m3)

  // ---- build CSR + permuted fp8 edge_attr + packed weights (loop-invariant) ----
  hipMemsetAsync(deg, 0, (size_t)N * sizeof(int), stream);
  hipMemsetAsync(cursor, 0, (size_t)N * sizeof(int), stream);
  hist_kernel<<<(E + 255) / 256, 256, 0, stream>>>(ei, deg, E);
  partial_kernel<<<nb, 256, 0, stream>>>(deg, partial, N);
  scanpart_kernel<<<1, 1024, 0, stream>>>(partial, nb);
  chunkscan_kernel<<<nb, 256, 0, stream>>>(deg, partial, off, N);
  scatter_conv_kernel<<<(E + 7) / 8, 256, 0, stream>>>(ei, ea, off, cursor, sperm, eap, E);
  pack_w_kernel<<<C, 256, 0, stream>>>(W1, W2, wpk);

  const int blocks = (N + BM - 1) / BM;
  const float* xc = x_in;
  for (int c = 0; c < C; ++c) {
    float* dst = (((C - 1 - c) & 1) == 0) ? (float*)d_out : xalt;
    layer_kernel<<<blocks, 256, 0, stream>>>(
        xc, eap, off, sperm, eps + c,
        wpk + (size_t)c * 4 * D * D,
        b1 + (size_t)c * D, b2 + (size_t)c * D,
        masks + (size_t)c * N,
        gamma + (size_t)c * D, beta + (size_t)c * D,
        rmean + (size_t)c * D, rvar + (size_t)c * D,
        x_in, dst, N, (c == C - 1) ? 1 : 0);
    xc = dst;
  }
}